// Round 7
// baseline (549.967 us; speedup 1.0000x reference)
//
#include <hip/hip_runtime.h>
#include <cstddef>
#include <type_traits>

// MediumLSTM v10: ZERO-BARRIER decomposition. 2048 fully independent waves
// (512 blocks x 4 waves), each owning 4 batch rows and running the whole
// L1->L2->L3 layer-delay pipeline privately. No s_barrier in the loop; the
// ~3500 cyc/step floor in v5..v9 tracked the per-step 4-wave barrier
// (phase-locked waves, 66 rendezvous), which this removes entirely.
//
// Layout: MFMA A carries 4-way ROW REPLICATION (lane nl holds row nl&3), so
// C holds rows in regs (acc[r] = row r, identical across qd replicas).
// Cells spread 2/lane: lane (n7,hi8,qd) owns cells (row=qd, unit=n7+8s+16*hi8)
// via cndmask reg-select (row=qd) + v8's shfl_xor(8) i/f|g/o exchange, with
// the tau (unit-half) selected by hi8.
// Weights: L1 (bw1, 8 taus x 4 kc) in VGPRs (128 regs). bh1 + all L2/L3
// weights in a block-shared read-only LDS pool (staged by wave 0, single
// init __syncthreads, then read-only forever -> no coherence issues).
// L2/L3 recurrent K-pack: a23 = [h2(16) | h3(8) | 0(8)] serves both.
//
// Per-wave per-step: 50 MFMA (4x replication waste - cheap, MfmaUtil was 7%),
// 4 cells-issue (2 L1 + 1 L2 + 1 L3-masked), 18 ds_read_b128, 0 barriers.
//
// Parity map (P = t&1), same delays as v4..v9, now all within ONE wave:
//   L1: reads h1s[1-P], xs[P];  writes h1s[P]    (h1[t])
//   L2: reads h1s[1-P], h2s[P]; writes h2s[1-P]  (h2[t-1])
//   L3: reads h2s[P], h3s[1-P]; writes h3s[P]    (h3[t-2])
//   FC: h3[63] lands in h3s[1] (iter 65).

typedef _Float16 h8_t  __attribute__((ext_vector_type(8)));
typedef __fp16   p2_t  __attribute__((ext_vector_type(2)));
typedef float    f4_t  __attribute__((ext_vector_type(4)));

#define T_LEN 64
#define D_IN  128
#define XS_STR 132   // x row stride in f16 (padded: banks spread, <=2-way)

__device__ __forceinline__ float rcp_(float x) { return __builtin_amdgcn_rcpf(x); }

// LSTM cell epilogue with shared reciprocals (v8, verified):
//   i*g = (e2g-1)*rcp((1+e^-vi)(e2g+1)); f = rcp(1+e^-vf)
//   h = o*tanh(c) = (e2c-1)*rcp((1+e^-vo)(e2c+1)), 2c clamped to +-30
__device__ __forceinline__ float cell_(float vi, float vf, float vg, float vo,
                                       float& c) {
    float eni = __expf(-vi);
    float enf = __expf(-vf);
    float eno = __expf(-vo);
    float e2g = __expf(2.0f * vg);
    float igg = (e2g - 1.0f) * rcp_((1.0f + eni) * (e2g + 1.0f));
    c = rcp_(1.0f + enf) * c + igg;
    float t2 = fminf(fmaxf(2.0f * c, -30.0f), 30.0f);
    float e2c = __expf(t2);
    return (e2c - 1.0f) * rcp_((1.0f + eno) * (e2c + 1.0f));
}

__device__ __forceinline__ h8_t zero8h() {
    h8_t r = { (_Float16)0.f,(_Float16)0.f,(_Float16)0.f,(_Float16)0.f,
               (_Float16)0.f,(_Float16)0.f,(_Float16)0.f,(_Float16)0.f };
    return r;
}
__device__ __forceinline__ h8_t cvt8(f4_t lo, f4_t hi) {
    union { h8_t v8; p2_t v2[4]; } u;
    u.v2[0] = __builtin_amdgcn_cvt_pkrtz(lo[0], lo[1]);
    u.v2[1] = __builtin_amdgcn_cvt_pkrtz(lo[2], lo[3]);
    u.v2[2] = __builtin_amdgcn_cvt_pkrtz(hi[0], hi[1]);
    u.v2[3] = __builtin_amdgcn_cvt_pkrtz(hi[2], hi[3]);
    return u.v8;
}
__device__ __forceinline__ h8_t load8f_h(const float* __restrict__ p) {
    f4_t lo = *(const f4_t*)p, hi = *(const f4_t*)(p + 4);
    return cvt8(lo, hi);
}

__global__ __launch_bounds__(256, 2)
void lstm_one(const float* __restrict__ x,
              const float* __restrict__ w_ih1, const float* __restrict__ w_hh1,
              const float* __restrict__ b_ih1, const float* __restrict__ b_hh1,
              const float* __restrict__ w_ih2, const float* __restrict__ w_hh2,
              const float* __restrict__ b_ih2, const float* __restrict__ b_hh2,
              const float* __restrict__ w_ih3, const float* __restrict__ w_hh3,
              const float* __restrict__ b_ih3, const float* __restrict__ b_hh3,
              const float* __restrict__ fc_w, const float* __restrict__ fc_b,
              float* __restrict__ out)
{
    // per-wave state [wid]...
    __shared__ __align__(16) _Float16 h1s[4][2][4][40];
    __shared__ __align__(16) _Float16 h2s[4][2][4][24];
    __shared__ __align__(16) _Float16 h3s[4][2][4][8];
    __shared__ __align__(16) _Float16 xs [4][2][4][XS_STR];
    // block-shared read-only weight pool: 18 frags x 64 lanes x 16B = 18KB
    //  0..3 : bw2[a][j]   (w_ih2)      4..7 : bhh2[a][j] (w_hh2, k<16)
    //  8..9 : b3c[j]      ([w_ih3|w_hh3|0])
    // 10..17: bh1[w][j]   (w_hh1)
    __shared__ __align__(16) _Float16 wpool[18][64][8];
    __shared__ __align__(16) _Float16 zpad[8];   // a23 qd==3 zero source

    const int tid  = threadIdx.x;          // 0..255
    const int lane = tid & 63;
    const int wid  = tid >> 6;             // 0..3 (independent waves)
    const int nl = lane & 15, qd = lane >> 4;
    const int n7 = nl & 7;
    const int hi8 = (nl >> 3) & 1;
    const bool lo8 = hi8 == 0;
    const int row4 = nl & 3;               // replicated data row in A-frags
    const bool q1 = (qd & 1) != 0, q2 = (qd & 2) != 0;

    // reg-select: pick row=qd from the 4 C-regs (replicas across qd)
    auto RS = [&](f4_t a) -> float {
        float t01 = q1 ? a[1] : a[0];
        float t23 = q1 ? a[3] : a[2];
        return q2 ? t23 : t01;
    };

    // ---------------- L1 weights (VGPR, all 8 taus) ----------------
    h8_t bw1[4][2][4];
    #pragma unroll
    for (int w = 0; w < 4; ++w)
    #pragma unroll
    for (int j = 0; j < 2; ++j) {
        int G = 8 * w + n7 + 32 * (hi8 + 2 * j);
        #pragma unroll
        for (int kc = 0; kc < 4; ++kc)
            bw1[w][j][kc] = load8f_h(w_ih1 + G * 128 + kc * 32 + qd * 8);
    }
    // ---------------- biases ----------------
    float bs1[2][4];
    #pragma unroll
    for (int s = 0; s < 2; ++s) {
        int u = n7 + 8 * s + 16 * hi8;
        #pragma unroll
        for (int g = 0; g < 4; ++g) bs1[s][g] = b_ih1[32 * g + u] + b_hh1[32 * g + u];
    }
    float bs2[4];
    {
        int u = n7 + 8 * hi8;
        #pragma unroll
        for (int g = 0; g < 4; ++g) bs2[g] = b_ih2[16 * g + u] + b_hh2[16 * g + u];
    }
    float bs3[4];
    #pragma unroll
    for (int g = 0; g < 4; ++g) bs3[g] = b_ih3[8 * g + n7] + b_hh3[8 * g + n7];

    // ---------------- stage weight pool (wave 0 only) ----------------
    if (wid == 0) {
        #pragma unroll
        for (int a = 0; a < 2; ++a)
        #pragma unroll
        for (int j = 0; j < 2; ++j) {
            int G2 = 8 * a + n7 + 16 * (hi8 + 2 * j);
            *(h8_t*)&wpool[2 * a + j][lane][0] = load8f_h(w_ih2 + G2 * 32 + qd * 8);
            h8_t v = (qd < 2) ? load8f_h(w_hh2 + G2 * 16 + qd * 8) : zero8h();
            *(h8_t*)&wpool[4 + 2 * a + j][lane][0] = v;
        }
        #pragma unroll
        for (int j = 0; j < 2; ++j) {
            int G3 = n7 + 8 * (hi8 + 2 * j);
            h8_t v = (qd < 2) ? load8f_h(w_ih3 + G3 * 16 + qd * 8)
                   : (qd == 2) ? load8f_h(w_hh3 + G3 * 8) : zero8h();
            *(h8_t*)&wpool[8 + j][lane][0] = v;
        }
        #pragma unroll
        for (int w = 0; w < 4; ++w)
        #pragma unroll
        for (int j = 0; j < 2; ++j) {
            int G = 8 * w + n7 + 32 * (hi8 + 2 * j);
            *(h8_t*)&wpool[10 + 2 * w + j][lane][0] = load8f_h(w_hh1 + G * 32 + qd * 8);
        }
    }
    // zero h-state (both parities) + zpad
    for (int i = tid; i < 4 * 2 * 4 * 40; i += 256) (&h1s[0][0][0][0])[i] = (_Float16)0.f;
    for (int i = tid; i < 4 * 2 * 4 * 24; i += 256) (&h2s[0][0][0][0])[i] = (_Float16)0.f;
    for (int i = tid; i < 4 * 2 * 4 * 8;  i += 256) (&h3s[0][0][0][0])[i] = (_Float16)0.f;
    if (tid < 8) zpad[tid] = (_Float16)0.f;

    // ---------------- x staging init (per-wave, private) ----------------
    const int b0r = (blockIdx.x * 4 + wid) * 4;     // this wave's first row
    const float* xrow = x + (size_t)(b0r + row4) * T_LEN * D_IN;
    const int chunk = (nl >> 2) + 4 * qd;           // 0..15 (8-float chunks)
    const float* xst = xrow + chunk * 8;

    f4_t xa0 = *(const f4_t*)xst, xa1 = *(const f4_t*)(xst + 4);   // x_0
    *(h8_t*)&xs[wid][0][row4][chunk * 8] = cvt8(xa0, xa1);
    xa0 = *(const f4_t*)(xst + D_IN);                               // x_1 -> regs
    xa1 = *(const f4_t*)(xst + D_IN + 4);

    __syncthreads();   // THE ONLY BARRIER: weight pool + zero-init visible

    float c1s[2] = {0.f, 0.f};   // L1 cells (s=0,1)
    float c2v = 0.f, c3v = 0.f;  // L2, L3 cells

    // ---------------- one pipelined iteration (no barriers) ----------------
    auto step = [&](auto d1c, auto d2c, auto d3c, auto pc, int t) {
        constexpr bool DO1 = decltype(d1c)::value;
        constexpr bool DO2 = decltype(d2c)::value;
        constexpr bool DO3 = decltype(d3c)::value;
        constexpr int  P   = decltype(pc)::value;

        h8_t a1p = zero8h(), a23 = zero8h();
        if constexpr (DO1 || DO2)
            a1p = *(const h8_t*)&h1s[wid][1 - P][row4][qd * 8];     // h1[t-1]
        if constexpr (DO2 || DO3) {
            const _Float16* ap = (qd < 2) ? &h2s[wid][P][row4][qd * 8]      // h2[t-2]
                              : (qd == 2) ? &h3s[wid][1 - P][row4][0]       // h3[t-3]
                                          : &zpad[0];
            a23 = *(const h8_t*)ap;
        }

        if constexpr (DO1) {
            h8_t af[4];
            #pragma unroll
            for (int kc = 0; kc < 4; ++kc)
                af[kc] = *(const h8_t*)&xs[wid][P][row4][kc * 32 + qd * 8];

            // stage x_{t+1} (regs) -> xs[1-P]; prefetch x_{t+2} -> regs
            h8_t xcur = cvt8(xa0, xa1);
            {
                int tn = (t + 2 < T_LEN) ? (t + 2) : (T_LEN - 1);
                xa0 = *(const f4_t*)(xst + (size_t)tn * D_IN);
                xa1 = *(const f4_t*)(xst + (size_t)tn * D_IN + 4);
            }
            *(h8_t*)&xs[wid][1 - P][row4][chunk * 8] = xcur;

            #pragma unroll
            for (int s = 0; s < 2; ++s) {
                // taus w=s (lo unit-half) and w=s+2 (hi unit-half)
                f4_t A[2][2];
                #pragma unroll
                for (int tw = 0; tw < 2; ++tw) {
                    int w = s + 2 * tw;
                    #pragma unroll
                    for (int j = 0; j < 2; ++j) {
                        h8_t wh = *(const h8_t*)&wpool[10 + 2 * w + j][lane][0];
                        f4_t a_ = {0.f, 0.f, 0.f, 0.f};
                        #pragma unroll
                        for (int kc = 0; kc < 4; ++kc)
                            a_ = __builtin_amdgcn_mfma_f32_16x16x32_f16(af[kc], bw1[w][j][kc], a_, 0, 0, 0);
                        a_ = __builtin_amdgcn_mfma_f32_16x16x32_f16(a1p, wh, a_, 0, 0, 0);
                        A[tw][j] = a_;
                    }
                }
                // extraction: own tau by hi8, row by reg-select, partner via xor8
                float ra0 = RS(A[0][0]), rb0 = RS(A[1][0]);
                float own0 = lo8 ? ra0 : rb0;
                float rec0 = __shfl_xor(lo8 ? rb0 : ra0, 8, 64);
                float ra1 = RS(A[0][1]), rb1 = RS(A[1][1]);
                float own1 = lo8 ? ra1 : rb1;
                float rec1 = __shfl_xor(lo8 ? rb1 : ra1, 8, 64);
                float vi = lo8 ? own0 : rec0;
                float vf = lo8 ? rec0 : own0;
                float vg = lo8 ? own1 : rec1;
                float vo = lo8 ? rec1 : own1;
                float h = cell_(vi + bs1[s][0], vf + bs1[s][1],
                                vg + bs1[s][2], vo + bs1[s][3], c1s[s]);
                h1s[wid][P][qd][n7 + 8 * s + 16 * hi8] = (_Float16)h;  // h1[t]
            }
        }

        if constexpr (DO2) {
            f4_t A[2][2];
            #pragma unroll
            for (int a = 0; a < 2; ++a)
            #pragma unroll
            for (int j = 0; j < 2; ++j) {
                h8_t wb = *(const h8_t*)&wpool[2 * a + j][lane][0];
                h8_t wh = *(const h8_t*)&wpool[4 + 2 * a + j][lane][0];
                f4_t a_ = {0.f, 0.f, 0.f, 0.f};
                a_ = __builtin_amdgcn_mfma_f32_16x16x32_f16(a1p, wb, a_, 0, 0, 0);
                a_ = __builtin_amdgcn_mfma_f32_16x16x32_f16(a23, wh, a_, 0, 0, 0);
                A[a][j] = a_;
            }
            float ra0 = RS(A[0][0]), rb0 = RS(A[1][0]);
            float own0 = lo8 ? ra0 : rb0;
            float rec0 = __shfl_xor(lo8 ? rb0 : ra0, 8, 64);
            float ra1 = RS(A[0][1]), rb1 = RS(A[1][1]);
            float own1 = lo8 ? ra1 : rb1;
            float rec1 = __shfl_xor(lo8 ? rb1 : ra1, 8, 64);
            float vi = lo8 ? own0 : rec0;
            float vf = lo8 ? rec0 : own0;
            float vg = lo8 ? own1 : rec1;
            float vo = lo8 ? rec1 : own1;
            float h = cell_(vi + bs2[0], vf + bs2[1], vg + bs2[2], vo + bs2[3], c2v);
            h2s[wid][1 - P][qd][n7 + 8 * hi8] = (_Float16)h;           // h2[t-1]
        }

        if constexpr (DO3) {
            f4_t A3[2];
            #pragma unroll
            for (int j = 0; j < 2; ++j) {
                h8_t wb = *(const h8_t*)&wpool[8 + j][lane][0];
                f4_t z = {0.f, 0.f, 0.f, 0.f};
                A3[j] = __builtin_amdgcn_mfma_f32_16x16x32_f16(a23, wb, z, 0, 0, 0);
            }
            // lo8 lanes own cells (row=qd, unit=n7); hi8 lanes supply f/o
            float r0 = RS(A3[0]), r1 = RS(A3[1]);
            float x0 = __shfl_xor(r0, 8, 64);
            float x1 = __shfl_xor(r1, 8, 64);
            float h = cell_(r0 + bs3[0], x0 + bs3[1], r1 + bs3[2], x1 + bs3[3], c3v);
            if (lo8) h3s[wid][P][qd][n7] = (_Float16)h;                // h3[t-2]
        }
    };

    using TT = std::integral_constant<bool, true>;
    using FF = std::integral_constant<bool, false>;
    using P0 = std::integral_constant<int, 0>;
    using P1 = std::integral_constant<int, 1>;

    // warm-up
    step(TT{}, FF{}, FF{}, P0{}, 0);
    step(TT{}, TT{}, FF{}, P1{}, 1);
    // main: t = 2..63, parity static via x2 unroll
    for (int tb = 1; tb < 32; ++tb) {
        step(TT{}, TT{}, TT{}, P0{}, 2 * tb);
        step(TT{}, TT{}, TT{}, P1{}, 2 * tb + 1);
    }
    // drain
    step(FF{}, TT{}, TT{}, P0{}, 64);
    step(FF{}, FF{}, TT{}, P1{}, 65);

    // ---------------- FC head: h3[63] is in h3s[wid][1] ----------------
    if (lane < 4) {
        float a = fc_b[0];
        #pragma unroll
        for (int u = 0; u < 8; ++u)
            a += fc_w[u] * (float)h3s[wid][1][lane][u];
        out[b0r + lane] = a;
    }
}

extern "C" void kernel_launch(void* const* d_in, const int* in_sizes, int n_in,
                              void* d_out, int out_size, void* d_ws, size_t ws_size,
                              hipStream_t stream) {
    (void)in_sizes; (void)n_in; (void)out_size; (void)d_ws; (void)ws_size;
    const float* x     = (const float*)d_in[0];
    const float* w_ih1 = (const float*)d_in[1];
    const float* w_hh1 = (const float*)d_in[2];
    const float* b_ih1 = (const float*)d_in[3];
    const float* b_hh1 = (const float*)d_in[4];
    const float* w_ih2 = (const float*)d_in[5];
    const float* w_hh2 = (const float*)d_in[6];
    const float* b_ih2 = (const float*)d_in[7];
    const float* b_hh2 = (const float*)d_in[8];
    const float* w_ih3 = (const float*)d_in[9];
    const float* w_hh3 = (const float*)d_in[10];
    const float* b_ih3 = (const float*)d_in[11];
    const float* b_hh3 = (const float*)d_in[12];
    const float* fc_w  = (const float*)d_in[13];
    const float* fc_b  = (const float*)d_in[14];

    dim3 grid(512), block(256);
    hipLaunchKernelGGL(lstm_one, grid, block, 0, stream,
                       x, w_ih1, w_hh1, b_ih1, b_hh1,
                       w_ih2, w_hh2, b_ih2, b_hh2,
                       w_ih3, w_hh3, b_ih3, b_hh3,
                       fc_w, fc_b, (float*)d_out);
}